// Round 1
// baseline (675.243 us; speedup 1.0000x reference)
//
#include <hip/hip_runtime.h>
#include <cmath>
#include <cstdint>
#include <cstddef>

#define N_NODES 50000
#define N_EDGES 800000
#define EN_TOT  (N_EDGES + N_NODES)   // edges + self loops
#define F1 256                         // HEADS*HID
#define F2 64                          // OUT

// ---------------------------------------------------------------- CSR build
__global__ void count_kernel(const int* __restrict__ ei, int* __restrict__ cnt) {
    int e = blockIdx.x * 256 + threadIdx.x;
    if (e >= EN_TOT) return;
    int dst = (e < N_EDGES) ? ei[N_EDGES + e] : (e - N_EDGES);
    atomicAdd(&cnt[dst], 1);
}

// single-block inclusive scan, 1024 threads, 8 elems/thread/pass
__global__ void scan_kernel(const int* __restrict__ cnt, int* __restrict__ rowptr, int n) {
    const int VPT = 8;
    __shared__ int buf[1024];
    __shared__ int carry_s;
    int t = threadIdx.x;
    if (t == 0) { carry_s = 0; rowptr[0] = 0; }
    __syncthreads();
    for (int base = 0; base < n; base += 1024 * VPT) {
        int v[VPT]; int local = 0;
        #pragma unroll
        for (int i = 0; i < VPT; ++i) {
            int idx = base + t * VPT + i;
            v[i] = (idx < n) ? cnt[idx] : 0;
            local += v[i];
        }
        buf[t] = local; __syncthreads();
        for (int off = 1; off < 1024; off <<= 1) {
            int x = (t >= off) ? buf[t - off] : 0;
            __syncthreads();
            buf[t] += x;
            __syncthreads();
        }
        int run = buf[t] - local + carry_s;   // exclusive prefix + carry
        #pragma unroll
        for (int i = 0; i < VPT; ++i) {
            int idx = base + t * VPT + i;
            run += v[i];
            if (idx < n) rowptr[idx + 1] = run;
        }
        __syncthreads();
        if (t == 1023) carry_s += buf[1023];
        __syncthreads();
    }
}

__global__ void fill_kernel(const int* __restrict__ ei, const int* __restrict__ rowptr,
                            int* __restrict__ cursor, int* __restrict__ col) {
    int e = blockIdx.x * 256 + threadIdx.x;
    if (e >= EN_TOT) return;
    int src, dst;
    if (e < N_EDGES) { src = ei[e]; dst = ei[N_EDGES + e]; }
    else             { src = dst = e - N_EDGES; }
    int pos = atomicAdd(&cursor[dst], 1);
    col[rowptr[dst] + pos] = src;
}

// ---------------------------------------------------------------- f32 GEMM
// C[M,N] = A[M,K] @ B[K,N]; 64x64 tile, BK=32, 256 threads, 4x4 micro-tile.
template <int BK>
__global__ void gemm_kernel(const float* __restrict__ A, const float* __restrict__ B,
                            float* __restrict__ C, int M, int N, int K) {
    __shared__ float As[BK][65];
    __shared__ float Bs[BK][65];
    const int tid = threadIdx.x;
    const int tx = tid & 15, ty = tid >> 4;
    const int brow = blockIdx.x * 64, bcol = blockIdx.y * 64;
    float acc[4][4] = {};
    for (int k0 = 0; k0 < K; k0 += BK) {
        #pragma unroll
        for (int i = tid; i < 64 * BK; i += 256) {
            int r = i / BK, c = i % BK;
            int gr = brow + r;
            As[c][r] = (gr < M) ? A[(size_t)gr * K + k0 + c] : 0.f;
        }
        #pragma unroll
        for (int i = tid; i < BK * 64; i += 256) {
            int r = i / 64, c = i % 64;
            Bs[r][c] = B[(size_t)(k0 + r) * N + bcol + c];
        }
        __syncthreads();
        #pragma unroll
        for (int kk = 0; kk < BK; ++kk) {
            float a[4], b[4];
            #pragma unroll
            for (int i = 0; i < 4; ++i) a[i] = As[kk][ty * 4 + i];
            #pragma unroll
            for (int j = 0; j < 4; ++j) b[j] = Bs[kk][tx * 4 + j];
            #pragma unroll
            for (int i = 0; i < 4; ++i)
                #pragma unroll
                for (int j = 0; j < 4; ++j) acc[i][j] += a[i] * b[j];
        }
        __syncthreads();
    }
    #pragma unroll
    for (int i = 0; i < 4; ++i) {
        int r = brow + ty * 4 + i;
        if (r < M) {
            float4 v = make_float4(acc[i][0], acc[i][1], acc[i][2], acc[i][3]);
            *(float4*)&C[(size_t)r * N + bcol + tx * 4] = v;
        }
    }
}

// ------------------------------------------------- per-node attention logits
// layer 1: heads=2, 128 feats each. one wave per node.
__global__ void alpha1_kernel(const float* __restrict__ h, const float* __restrict__ a_src,
                              const float* __restrict__ a_dst,
                              float* __restrict__ asrc, float* __restrict__ adst) {
    int n = blockIdx.x;
    int l = threadIdx.x;                 // 64
    int head = l >> 5;                   // 0..31 -> head0, 32..63 -> head1
    int lf = (l & 31) * 4;
    const float4 hv = *(const float4*)(h + (size_t)n * F1 + head * 128 + lf);
    const float4 as = *(const float4*)(a_src + head * 128 + lf);
    const float4 ad = *(const float4*)(a_dst + head * 128 + lf);
    float ps = hv.x * as.x + hv.y * as.y + hv.z * as.z + hv.w * as.w;
    float pd = hv.x * ad.x + hv.y * ad.y + hv.z * ad.z + hv.w * ad.w;
    #pragma unroll
    for (int off = 1; off < 32; off <<= 1) {
        ps += __shfl_xor(ps, off);
        pd += __shfl_xor(pd, off);
    }
    if ((l & 31) == 0) {
        asrc[n * 2 + head] = ps;
        adst[n * 2 + head] = pd;
    }
}

// layer 2: 1 head, 64 feats. one wave per node.
__global__ void alpha2_kernel(const float* __restrict__ g, const float* __restrict__ a_src,
                              const float* __restrict__ a_dst,
                              float* __restrict__ asrc, float* __restrict__ adst) {
    int n = blockIdx.x;
    int l = threadIdx.x;                 // 64
    float v = g[(size_t)n * F2 + l];
    float ps = v * a_src[l];
    float pd = v * a_dst[l];
    #pragma unroll
    for (int off = 1; off < 64; off <<= 1) {
        ps += __shfl_xor(ps, off);
        pd += __shfl_xor(pd, off);
    }
    if (l == 0) { asrc[n] = ps; adst[n] = pd; }
}

__device__ __forceinline__ float lrelu(float x) { return x > 0.f ? x : 0.2f * x; }

// ---------------------------------------------------- layer-1 aggregation
// one block (256 threads) per destination node; thread t owns feature t.
__global__ void agg1_kernel(const float* __restrict__ h, const float* __restrict__ asrc,
                            const float* __restrict__ adst, const int* __restrict__ rowptr,
                            const int* __restrict__ col, const float* __restrict__ b1,
                            float* __restrict__ h1) {
    int n = blockIdx.x;
    int t = threadIdx.x;
    int beg = rowptr[n], end = rowptr[n + 1];
    float ad0 = adst[n * 2 + 0], ad1 = adst[n * 2 + 1];

    __shared__ float sstat[4];           // m0,s0,m1,s1
    if (t < 64) {
        float m0 = -INFINITY, s0 = 0.f, m1 = -INFINITY, s1 = 0.f;
        for (int k = beg + t; k < end; k += 64) {
            int src = col[k];
            float e0 = lrelu(asrc[src * 2 + 0] + ad0);
            float e1 = lrelu(asrc[src * 2 + 1] + ad1);
            float nm0 = fmaxf(m0, e0);
            s0 = s0 * expf(m0 - nm0) + expf(e0 - nm0); m0 = nm0;
            float nm1 = fmaxf(m1, e1);
            s1 = s1 * expf(m1 - nm1) + expf(e1 - nm1); m1 = nm1;
        }
        #pragma unroll
        for (int off = 1; off < 64; off <<= 1) {
            float om0 = __shfl_xor(m0, off), os0 = __shfl_xor(s0, off);
            float nm0 = fmaxf(m0, om0);
            s0 = (nm0 == -INFINITY) ? 0.f : (s0 * expf(m0 - nm0) + os0 * expf(om0 - nm0));
            m0 = nm0;
            float om1 = __shfl_xor(m1, off), os1 = __shfl_xor(s1, off);
            float nm1 = fmaxf(m1, om1);
            s1 = (nm1 == -INFINITY) ? 0.f : (s1 * expf(m1 - nm1) + os1 * expf(om1 - nm1));
            m1 = nm1;
        }
        if (t == 0) { sstat[0] = m0; sstat[1] = s0; sstat[2] = m1; sstat[3] = s1; }
    }
    __syncthreads();
    float fm0 = sstat[0], fi0 = 1.f / sstat[1];
    float fm1 = sstat[2], fi1 = 1.f / sstat[3];

    __shared__ int   s_src[256];
    __shared__ float s_al0[256];
    __shared__ float s_al1[256];
    int head = t >> 7;
    float acc = 0.f;
    for (int base = beg; base < end; base += 256) {
        int cnt = min(256, end - base);
        if (t < cnt) {
            int src = col[base + t];
            s_src[t] = src;
            float e0 = lrelu(asrc[src * 2 + 0] + ad0);
            float e1 = lrelu(asrc[src * 2 + 1] + ad1);
            s_al0[t] = expf(e0 - fm0) * fi0;
            s_al1[t] = expf(e1 - fm1) * fi1;
        }
        __syncthreads();
        const float* alp = head ? s_al1 : s_al0;
        for (int i = 0; i < cnt; ++i)
            acc += alp[i] * h[(size_t)s_src[i] * F1 + t];
        __syncthreads();
    }
    float v = acc + b1[t];
    h1[(size_t)n * F1 + t] = v > 0.f ? v : expm1f(v);   // ELU, alpha=1
}

// ---------------------------------------------------- layer-2 aggregation
// one wave per node; thread t owns feature t (64 feats, 1 head). +b2 fused.
__global__ void agg2_kernel(const float* __restrict__ g, const float* __restrict__ asrc,
                            const float* __restrict__ adst, const int* __restrict__ rowptr,
                            const int* __restrict__ col, const float* __restrict__ b2,
                            float* __restrict__ out) {
    int n = blockIdx.x;
    int t = threadIdx.x;                 // 64
    int beg = rowptr[n], end = rowptr[n + 1];
    float ad = adst[n];

    float m = -INFINITY, s = 0.f;
    for (int k = beg + t; k < end; k += 64) {
        int src = col[k];
        float e = lrelu(asrc[src] + ad);
        float nm = fmaxf(m, e);
        s = s * expf(m - nm) + expf(e - nm); m = nm;
    }
    #pragma unroll
    for (int off = 1; off < 64; off <<= 1) {
        float om = __shfl_xor(m, off), os = __shfl_xor(s, off);
        float nm = fmaxf(m, om);
        s = (nm == -INFINITY) ? 0.f : (s * expf(m - nm) + os * expf(om - nm));
        m = nm;
    }
    float inv = 1.f / s;

    __shared__ int   s_src[64];
    __shared__ float s_al[64];
    float acc = 0.f;
    for (int base = beg; base < end; base += 64) {
        int cnt = min(64, end - base);
        if (t < cnt) {
            int src = col[base + t];
            s_src[t] = src;
            float e = lrelu(asrc[src] + ad);
            s_al[t] = expf(e - m) * inv;
        }
        __syncthreads();
        for (int i = 0; i < cnt; ++i)
            acc += s_al[i] * g[(size_t)s_src[i] * F2 + t];
        __syncthreads();
    }
    out[(size_t)n * F2 + t] = acc + b2[t];
}

// ---------------------------------------------------------------- launch
extern "C" void kernel_launch(void* const* d_in, const int* in_sizes, int n_in,
                              void* d_out, int out_size, void* d_ws, size_t ws_size,
                              hipStream_t stream) {
    const float* x      = (const float*)d_in[0];
    const int*   ei     = (const int*)d_in[1];     // [2, E] flat: row0=src, row1=dst
    const float* W1     = (const float*)d_in[2];
    const float* a_src1 = (const float*)d_in[3];
    const float* a_dst1 = (const float*)d_in[4];
    const float* b1     = (const float*)d_in[5];
    const float* W2     = (const float*)d_in[6];
    const float* a_src2 = (const float*)d_in[7];
    const float* a_dst2 = (const float*)d_in[8];
    const float* b2     = (const float*)d_in[9];
    float* out = (float*)d_out;

    char* ws = (char*)d_ws;
    size_t off = 0;
    auto alloc = [&](size_t bytes) -> void* {
        void* p = ws + off;
        off = (off + bytes + 255) & ~(size_t)255;
        return p;
    };
    float* h      = (float*)alloc((size_t)N_NODES * F1 * 4);
    float* h1     = (float*)alloc((size_t)N_NODES * F1 * 4);
    float* g      = (float*)alloc((size_t)N_NODES * F2 * 4);
    float* asrc1  = (float*)alloc((size_t)N_NODES * 2 * 4);
    float* adst1  = (float*)alloc((size_t)N_NODES * 2 * 4);
    float* asrc2  = (float*)alloc((size_t)N_NODES * 4);
    float* adst2  = (float*)alloc((size_t)N_NODES * 4);
    int*   rowptr = (int*)alloc((size_t)(N_NODES + 1) * 4);
    int*   cnt    = (int*)alloc((size_t)N_NODES * 4);
    int*   cursor = (int*)alloc((size_t)N_NODES * 4);
    int*   col    = (int*)alloc((size_t)EN_TOT * 4);

    hipMemsetAsync(cnt, 0, (size_t)N_NODES * 4, stream);
    hipMemsetAsync(cursor, 0, (size_t)N_NODES * 4, stream);

    const int eb = (EN_TOT + 255) / 256;
    count_kernel<<<eb, 256, 0, stream>>>(ei, cnt);
    scan_kernel<<<1, 1024, 0, stream>>>(cnt, rowptr, N_NODES);
    fill_kernel<<<eb, 256, 0, stream>>>(ei, rowptr, cursor, col);

    const int mb = (N_NODES + 63) / 64;
    gemm_kernel<32><<<dim3(mb, F1 / 64), 256, 0, stream>>>(x, W1, h, N_NODES, F1, 256);
    alpha1_kernel<<<N_NODES, 64, 0, stream>>>(h, a_src1, a_dst1, asrc1, adst1);
    agg1_kernel<<<N_NODES, 256, 0, stream>>>(h, asrc1, adst1, rowptr, col, b1, h1);

    gemm_kernel<32><<<dim3(mb, 1), 256, 0, stream>>>(h1, W2, g, N_NODES, F2, 256);
    alpha2_kernel<<<N_NODES, 64, 0, stream>>>(g, a_src2, a_dst2, asrc2, adst2);
    agg2_kernel<<<N_NODES, 64, 0, stream>>>(g, asrc2, adst2, rowptr, col, b2, out);
}